// Round 3
// baseline (10866.361 us; speedup 1.0000x reference)
//
#include <hip/hip_runtime.h>

#define SLOPE 0.22916666666666666f  // (1/8 + 1/3) / 2
#define ALONE_CAP 8192              // expected alone nodes ~2.3; capacity is overkill-safe

// ---------------------------------------------------------------- CSR build
__global__ __launch_bounds__(256) void count_kernel(const int* __restrict__ dst,
                                                    int* __restrict__ deg, int e) {
    int i = blockIdx.x * 256 + threadIdx.x;
    if (i < e) atomicAdd(&deg[dst[i]], 1);
}

// --- 3-kernel exclusive scan over deg[n] -> row_off[n+1] (chunk = 1024) ---
__global__ __launch_bounds__(256) void scan_partial_kernel(const int* __restrict__ deg,
                                                           int* __restrict__ partial, int n) {
    __shared__ int wsum[4];
    int base = blockIdx.x * 1024;
    int t = threadIdx.x;
    int s = 0;
    #pragma unroll
    for (int j = 0; j < 4; ++j) {
        int i = base + t + 256 * j;
        if (i < n) s += deg[i];
    }
    #pragma unroll
    for (int off = 1; off < 64; off <<= 1) s += __shfl_xor(s, off, 64);
    if ((t & 63) == 0) wsum[t >> 6] = s;
    __syncthreads();
    if (t == 0) partial[blockIdx.x] = wsum[0] + wsum[1] + wsum[2] + wsum[3];
}

__global__ __launch_bounds__(64) void scan_aux_kernel(int* __restrict__ partial, int nparts) {
    int t = threadIdx.x;  // nparts <= 64 (n <= 65536)
    int v = (t < nparts) ? partial[t] : 0;
    int x = v;
    #pragma unroll
    for (int off = 1; off < 64; off <<= 1) {
        int y = __shfl_up(x, off, 64);
        if (t >= off) x += y;
    }
    if (t < nparts) partial[t] = x - v;  // exclusive
}

__global__ __launch_bounds__(256) void scan_final_kernel(const int* __restrict__ deg,
                                                         const int* __restrict__ partial,
                                                         int* __restrict__ row_off, int n) {
    __shared__ int wsum[4];
    int base = blockIdx.x * 1024;
    int t = threadIdx.x, lane = t & 63, wid = t >> 6;
    int i0 = base + t * 4;
    int v0 = (i0 + 0 < n) ? deg[i0 + 0] : 0;
    int v1 = (i0 + 1 < n) ? deg[i0 + 1] : 0;
    int v2 = (i0 + 2 < n) ? deg[i0 + 2] : 0;
    int v3 = (i0 + 3 < n) ? deg[i0 + 3] : 0;
    int s = v0 + v1 + v2 + v3;
    int x = s;
    #pragma unroll
    for (int off = 1; off < 64; off <<= 1) {
        int y = __shfl_up(x, off, 64);
        if (lane >= off) x += y;
    }
    if (lane == 63) wsum[wid] = x;
    __syncthreads();
    int wbase = 0;
    #pragma unroll
    for (int w = 0; w < 4; ++w) { int ws = wsum[w]; if (w < wid) wbase += ws; }
    int p = partial[blockIdx.x] + wbase + x - s;  // exclusive prefix at i0
    if (i0 + 0 <= n) row_off[i0 + 0] = p;
    p += v0;
    if (i0 + 1 <= n) row_off[i0 + 1] = p;
    p += v1;
    if (i0 + 2 <= n) row_off[i0 + 2] = p;
    p += v2;
    if (i0 + 3 <= n) row_off[i0 + 3] = p;
}

__global__ __launch_bounds__(256) void scatter_kernel(
    const int* __restrict__ src, const int* __restrict__ dst,
    const int* __restrict__ ety, const int* __restrict__ row_off,
    int* __restrict__ cursor, int2* __restrict__ edges, int e) {
    int i = blockIdx.x * 256 + threadIdx.x;
    if (i < e) {
        int v = dst[i];
        int pos = row_off[v] + atomicAdd(&cursor[v], 1);
        edges[pos] = make_int2(src[i], ety[i]);
    }
}

__global__ __launch_bounds__(256) void flag_kernel(const int* __restrict__ deg,
                                                   int* __restrict__ alone_list,
                                                   int* __restrict__ alone_count, int n) {
    int i = blockIdx.x * 256 + threadIdx.x;
    if (i < n && deg[i] == 0) {
        int p = atomicAdd(alone_count, 1);
        if (p < ALONE_CAP) alone_list[p] = i;
    }
}

// ------------------------------------------------------- per-layer kernels
// S[v] = norm[v] * sum_{e: dst=v} (h[src_e] + rel[etype_e])
// One wave per node, float2 per lane. 4 nodes per 256-thread block.
__global__ __launch_bounds__(256) void agg_kernel(
    const float* __restrict__ h, const float* __restrict__ rel,
    const float* __restrict__ norm, const int* __restrict__ row_off,
    const int2* __restrict__ edges, float* __restrict__ S, int n) {
    int wave = threadIdx.x >> 6, lane = threadIdx.x & 63;
    int v = blockIdx.x * 4 + wave;
    if (v >= n) return;
    int s0 = row_off[v], s1 = row_off[v + 1];
    int c2 = lane * 2;
    float ax = 0.f, ay = 0.f;
    int e = s0;
    for (; e + 1 < s1; e += 2) {
        int2 e0 = edges[e], e1 = edges[e + 1];
        float2 h0 = *(const float2*)&h[(size_t)e0.x * 128 + c2];
        float2 r0 = *(const float2*)&rel[(size_t)e0.y * 128 + c2];
        float2 h1 = *(const float2*)&h[(size_t)e1.x * 128 + c2];
        float2 r1 = *(const float2*)&rel[(size_t)e1.y * 128 + c2];
        ax += h0.x + r0.x; ay += h0.y + r0.y;
        ax += h1.x + r1.x; ay += h1.y + r1.y;
    }
    if (e < s1) {
        int2 e0 = edges[e];
        float2 h0 = *(const float2*)&h[(size_t)e0.x * 128 + c2];
        float2 r0 = *(const float2*)&rel[(size_t)e0.y * 128 + c2];
        ax += h0.x + r0.x; ay += h0.y + r0.y;
    }
    float nm = norm[v];
    *(float2*)&S[(size_t)v * 128 + c2] = make_float2(ax * nm, ay * nm);
}

// out = leaky(S @ Wn + H @ Wl). 32x128 tile per block, 256 threads,
// 2 rows x 8 cols per thread. Grid = ceil(n/32) = 1563 -> ~6 blocks/CU.
// NOTE: H and out may alias (h1 lives in d_out) — no __restrict__ on them.
// Safe: each block reads H only in its own 32-row range (clamped row n-1
// belongs to the last block, which owns it), all reads precede stores.
__global__ __launch_bounds__(256) void gemm_kernel(
    const float* __restrict__ S, const float* H,
    const float* __restrict__ Wn, const float* __restrict__ Wl,
    float* out, int n) {
    __shared__ float Asm[32][34];    // [k][row], pad 34: staging writes 2-way (free)
    __shared__ float Wsm[32][132];   // [k][col], pad for 16B-aligned float4
    const int tid = threadIdx.x;
    const int wave = tid >> 6, lane = tid & 63;
    const int tr = lane >> 4;        // 0..3
    const int tc = lane & 15;        // 0..15
    const int lrow = wave * 8 + tr * 2;  // 0..30, even
    const int lcol = tc * 8;
    const int row0 = blockIdx.x * 32;

    // A staging coords: thread -> (r, k4)
    const int sr = tid >> 3;             // 0..31
    const int sk4 = (tid & 7) << 2;      // 0,4,...,28
    int gr = row0 + sr;
    if (gr >= n) gr = n - 1;

    float acc[2][8];
    #pragma unroll
    for (int i = 0; i < 2; ++i)
        #pragma unroll
        for (int j = 0; j < 8; ++j) acc[i][j] = 0.f;

    #pragma unroll
    for (int pass = 0; pass < 2; ++pass) {
        const float* A = pass ? H : S;
        const float* __restrict__ W = pass ? Wl : Wn;
        #pragma unroll
        for (int k0 = 0; k0 < 128; k0 += 32) {
            __syncthreads();
            // stage A: 32 rows x 32 k, transposed
            float4 av = *(const float4*)(A + (size_t)gr * 128 + k0 + sk4);
            Asm[sk4 + 0][sr] = av.x;
            Asm[sk4 + 1][sr] = av.y;
            Asm[sk4 + 2][sr] = av.z;
            Asm[sk4 + 3][sr] = av.w;
            // stage W: 32 k x 128 cols
            #pragma unroll
            for (int q = 0; q < 4; ++q) {
                int idx = tid + 256 * q;       // 0..1023
                int kr = idx >> 5;             // 0..31
                int c4 = (idx & 31) << 2;      // 0..124
                *(float4*)&Wsm[kr][c4] = *(const float4*)(W + (size_t)(k0 + kr) * 128 + c4);
            }
            __syncthreads();
            #pragma unroll
            for (int k = 0; k < 32; ++k) {
                float2 a = *(const float2*)&Asm[k][lrow];
                float4 w0 = *(const float4*)&Wsm[k][lcol];
                float4 w1 = *(const float4*)&Wsm[k][lcol + 4];
                float w[8] = {w0.x, w0.y, w0.z, w0.w, w1.x, w1.y, w1.z, w1.w};
                #pragma unroll
                for (int j = 0; j < 8; ++j) {
                    acc[0][j] += a.x * w[j];
                    acc[1][j] += a.y * w[j];
                }
            }
        }
    }

    #pragma unroll
    for (int i = 0; i < 2; ++i) {
        int r = row0 + lrow + i;
        if (r < n) {
            float o[8];
            #pragma unroll
            for (int j = 0; j < 8; ++j) {
                float v = acc[i][j];
                o[j] = v >= 0.f ? v : v * SLOPE;
            }
            *(float4*)(out + (size_t)r * 128 + lcol)     = make_float4(o[0], o[1], o[2], o[3]);
            *(float4*)(out + (size_t)r * 128 + lcol + 4) = make_float4(o[4], o[5], o[6], o[7]);
        }
    }
}

// Snapshot h rows of alone nodes before the GEMM clobbers them (h may alias out).
__global__ __launch_bounds__(128) void save_alone_kernel(
    const float* __restrict__ H, const int* __restrict__ alone_list,
    const int* __restrict__ alone_count, float* __restrict__ asave) {
    int cnt = *alone_count;
    if (cnt > ALONE_CAP) cnt = ALONE_CAP;
    int t = threadIdx.x;
    for (int i = blockIdx.x; i < cnt; i += gridDim.x) {
        int v = alone_list[i];
        asave[i * 128 + t] = H[v * 128 + t];
    }
}

// For alone nodes: out[v] = leaky(hrow @ Wa). Hrows indexed by node id when
// by_node != 0 (layer 1, reads ent), else by list position (layer 2 snapshot).
__global__ __launch_bounds__(128) void fixup_kernel(
    const float* __restrict__ Hrows, int by_node,
    const float* __restrict__ Wa,
    const int* __restrict__ alone_list, const int* __restrict__ alone_count,
    float* out) {
    int cnt = *alone_count;
    if (cnt > ALONE_CAP) cnt = ALONE_CAP;
    int t = threadIdx.x;
    for (int i = blockIdx.x; i < cnt; i += gridDim.x) {
        int v = alone_list[i];
        const float* hrow = Hrows + (size_t)(by_node ? v : i) * 128;
        float acc = 0.f;
        for (int k = 0; k < 128; ++k)
            acc += hrow[k] * Wa[k * 128 + t];
        out[v * 128 + t] = acc >= 0.f ? acc : acc * SLOPE;
    }
}

extern "C" void kernel_launch(void* const* d_in, const int* in_sizes, int n_in,
                              void* d_out, int out_size, void* d_ws, size_t ws_size,
                              hipStream_t stream) {
    const float* ent  = (const float*)d_in[0];
    const float* rel  = (const float*)d_in[1];
    const float* norm = (const float*)d_in[2];
    const float* Wn   = (const float*)d_in[3];
    const float* Wl   = (const float*)d_in[4];
    const float* Wa   = (const float*)d_in[5];
    const int*   src  = (const int*)d_in[6];
    const int*   dst  = (const int*)d_in[7];
    const int*   ety  = (const int*)d_in[8];
    float* out = (float*)d_out;

    const int n = in_sizes[2];   // 50000
    const int e = in_sizes[7];   // 500000

    // workspace layout
    char* ws = (char*)d_ws;
    int* deg         = (int*)ws;          // n
    int* cursor      = deg + n;           // n
    int* alone_count = cursor + n;        // 1
    size_t zbytes = (size_t)(2 * n + 1) * sizeof(int);
    size_t p = (zbytes + 255) & ~(size_t)255;
    int* row_off = (int*)(ws + p);        // n+1
    p += (((size_t)(n + 1) * 4) + 255) & ~(size_t)255;
    int* partial = (int*)(ws + p);        // <=64
    p += 256;
    int* alone_list = (int*)(ws + p);     // ALONE_CAP
    p += (((size_t)ALONE_CAP * 4) + 255) & ~(size_t)255;
    float* asave = (float*)(ws + p);      // ALONE_CAP*128 floats
    p += (((size_t)ALONE_CAP * 128 * 4) + 255) & ~(size_t)255;
    int2* edges = (int2*)(ws + p);        // e
    p += (((size_t)e * 8) + 255) & ~(size_t)255;
    float* Sbuf = (float*)(ws + p);       // n*128
    float* h1 = out;                      // intermediate h lives in d_out

    const int eb = (e + 255) / 256;
    const int nb = (n + 255) / 256;
    const int nparts = (n + 1023) / 1024;       // 49 (<=64 required)
    const int gb = (n + 31) / 32;               // 1563
    const int ab = (n + 3) / 4;                 // 12500

    hipMemsetAsync(ws, 0, zbytes, stream);
    count_kernel<<<eb, 256, 0, stream>>>(dst, deg, e);
    scan_partial_kernel<<<nparts, 256, 0, stream>>>(deg, partial, n);
    scan_aux_kernel<<<1, 64, 0, stream>>>(partial, nparts);
    scan_final_kernel<<<nparts, 256, 0, stream>>>(deg, partial, row_off, n);
    scatter_kernel<<<eb, 256, 0, stream>>>(src, dst, ety, row_off, cursor, edges, e);
    flag_kernel<<<nb, 256, 0, stream>>>(deg, alone_list, alone_count, n);

    // layer 0: h0 = ent -> h1 (in d_out). fixup reads ent (not aliased).
    agg_kernel<<<ab, 256, 0, stream>>>(ent, rel, norm, row_off, edges, Sbuf, n);
    gemm_kernel<<<gb, 256, 0, stream>>>(Sbuf, ent, Wn, Wl, h1, n);
    fixup_kernel<<<16, 128, 0, stream>>>(ent, 1, Wa, alone_list, alone_count, h1);

    // layer 1: h1 -> out (aliases). Snapshot alone rows BEFORE gemm clobbers h1.
    agg_kernel<<<ab, 256, 0, stream>>>(h1, rel, norm, row_off, edges, Sbuf, n);
    save_alone_kernel<<<16, 128, 0, stream>>>(h1, alone_list, alone_count, asave);
    gemm_kernel<<<gb, 256, 0, stream>>>(Sbuf, h1, Wn + 16384, Wl + 16384, out, n);
    fixup_kernel<<<16, 128, 0, stream>>>(asave, 0, Wa + 16384, alone_list, alone_count, out);
}

// Round 4
// 357.397 us; speedup vs baseline: 30.4042x; 30.4042x over previous
//
#include <hip/hip_runtime.h>

#define SLOPE 0.22916666666666666f  // (1/8 + 1/3) / 2
#define ALONE_CAP 8192              // expected alone nodes ~2.3; capacity is overkill-safe

// ---------------------------------------------------------------- CSR build
__global__ __launch_bounds__(256) void count_kernel(const int* __restrict__ dst,
                                                    int* __restrict__ deg, int e) {
    int i = blockIdx.x * 256 + threadIdx.x;
    if (i < e) atomicAdd(&deg[dst[i]], 1);
}

// --- 3-kernel exclusive scan over deg[n] -> row_off[n+1] (chunk = 1024) ---
__global__ __launch_bounds__(256) void scan_partial_kernel(const int* __restrict__ deg,
                                                           int* __restrict__ partial, int n) {
    __shared__ int wsum[4];
    int base = blockIdx.x * 1024;
    int t = threadIdx.x;
    int s = 0;
    #pragma unroll
    for (int j = 0; j < 4; ++j) {
        int i = base + t + 256 * j;
        if (i < n) s += deg[i];
    }
    #pragma unroll
    for (int off = 1; off < 64; off <<= 1) s += __shfl_xor(s, off, 64);
    if ((t & 63) == 0) wsum[t >> 6] = s;
    __syncthreads();
    if (t == 0) partial[blockIdx.x] = wsum[0] + wsum[1] + wsum[2] + wsum[3];
}

__global__ __launch_bounds__(64) void scan_aux_kernel(int* __restrict__ partial, int nparts) {
    int t = threadIdx.x;  // nparts <= 64 (n <= 65536)
    int v = (t < nparts) ? partial[t] : 0;
    int x = v;
    #pragma unroll
    for (int off = 1; off < 64; off <<= 1) {
        int y = __shfl_up(x, off, 64);
        if (t >= off) x += y;
    }
    if (t < nparts) partial[t] = x - v;  // exclusive
}

__global__ __launch_bounds__(256) void scan_final_kernel(const int* __restrict__ deg,
                                                         const int* __restrict__ partial,
                                                         int* __restrict__ row_off, int n) {
    __shared__ int wsum[4];
    int base = blockIdx.x * 1024;
    int t = threadIdx.x, lane = t & 63, wid = t >> 6;
    int i0 = base + t * 4;
    int v0 = (i0 + 0 < n) ? deg[i0 + 0] : 0;
    int v1 = (i0 + 1 < n) ? deg[i0 + 1] : 0;
    int v2 = (i0 + 2 < n) ? deg[i0 + 2] : 0;
    int v3 = (i0 + 3 < n) ? deg[i0 + 3] : 0;
    int s = v0 + v1 + v2 + v3;
    int x = s;
    #pragma unroll
    for (int off = 1; off < 64; off <<= 1) {
        int y = __shfl_up(x, off, 64);
        if (lane >= off) x += y;
    }
    if (lane == 63) wsum[wid] = x;
    __syncthreads();
    int wbase = 0;
    #pragma unroll
    for (int w = 0; w < 4; ++w) { int ws = wsum[w]; if (w < wid) wbase += ws; }
    int p = partial[blockIdx.x] + wbase + x - s;  // exclusive prefix at i0
    if (i0 + 0 <= n) row_off[i0 + 0] = p;
    p += v0;
    if (i0 + 1 <= n) row_off[i0 + 1] = p;
    p += v1;
    if (i0 + 2 <= n) row_off[i0 + 2] = p;
    p += v2;
    if (i0 + 3 <= n) row_off[i0 + 3] = p;
}

__global__ __launch_bounds__(256) void scatter_kernel(
    const int* __restrict__ src, const int* __restrict__ dst,
    const int* __restrict__ ety, const int* __restrict__ row_off,
    int* __restrict__ cursor, int2* __restrict__ edges, int e) {
    int i = blockIdx.x * 256 + threadIdx.x;
    if (i < e) {
        int v = dst[i];
        int pos = row_off[v] + atomicAdd(&cursor[v], 1);
        edges[pos] = make_int2(src[i], ety[i]);
    }
}

__global__ __launch_bounds__(256) void flag_kernel(const int* __restrict__ deg,
                                                   int* __restrict__ alone_list,
                                                   int* __restrict__ alone_count, int n) {
    int i = blockIdx.x * 256 + threadIdx.x;
    if (i < n && deg[i] == 0) {
        int p = atomicAdd(alone_count, 1);
        if (p < ALONE_CAP) alone_list[p] = i;
    }
}

// ------------------------------------------------------- per-layer kernels
// S[v] = norm[v] * sum_{e: dst=v} (h[src_e] + rel[etype_e])
// One wave per node; 2 edges in flight (half-wave each), float4 per lane.
__global__ __launch_bounds__(256) void agg_kernel(
    const float* __restrict__ h, const float* __restrict__ rel,
    const float* __restrict__ norm, const int* __restrict__ row_off,
    const int2* __restrict__ edges, float* __restrict__ S, int n) {
    int wave = threadIdx.x >> 6, lane = threadIdx.x & 63;
    int v = blockIdx.x * 4 + wave;
    if (v >= n) return;
    int s0 = row_off[v], s1 = row_off[v + 1];
    int half = lane >> 5;            // 0 or 1: which edge of the pair
    int c4 = (lane & 31) * 4;        // column group 0..124
    float4 acc = make_float4(0.f, 0.f, 0.f, 0.f);
    int e = s0;
    for (; e + 1 < s1; e += 2) {
        int2 ed = edges[e + half];
        float4 hv = *(const float4*)&h[(size_t)ed.x * 128 + c4];
        float4 rv = *(const float4*)&rel[(size_t)ed.y * 128 + c4];
        acc.x += hv.x + rv.x; acc.y += hv.y + rv.y;
        acc.z += hv.z + rv.z; acc.w += hv.w + rv.w;
    }
    if (e < s1 && half == 0) {       // odd tail: half 0 only
        int2 ed = edges[e];
        float4 hv = *(const float4*)&h[(size_t)ed.x * 128 + c4];
        float4 rv = *(const float4*)&rel[(size_t)ed.y * 128 + c4];
        acc.x += hv.x + rv.x; acc.y += hv.y + rv.y;
        acc.z += hv.z + rv.z; acc.w += hv.w + rv.w;
    }
    // combine the two halves (lane i and i+32 hold same columns)
    acc.x += __shfl_xor(acc.x, 32, 64);
    acc.y += __shfl_xor(acc.y, 32, 64);
    acc.z += __shfl_xor(acc.z, 32, 64);
    acc.w += __shfl_xor(acc.w, 32, 64);
    if (half == 0) {
        float nm = norm[v];
        acc.x *= nm; acc.y *= nm; acc.z *= nm; acc.w *= nm;
        *(float4*)&S[(size_t)v * 128 + c4] = acc;
    }
}

// out = leaky(S @ Wn + H @ Wl). 64x128 tile per block, 256 threads,
// 4 rows x 8 cols per thread. Grid = ceil(n/64) = 782 -> ~3 blocks/CU.
// Structure matches the round-2 kernel that measured 92 VGPRs / no spill:
// NO pragma on pass/k0 loops, full unroll only on innermost k loop.
// NOTE: H and out may alias (h1 lives in d_out) — no __restrict__ on them.
// Safe: each block reads H only in its own 64-row range (the clamped row
// n-1 belongs to the last block, which owns it); all reads precede stores.
__global__ __launch_bounds__(256) void gemm_kernel(
    const float* __restrict__ S, const float* H,
    const float* __restrict__ Wn, const float* __restrict__ Wl,
    float* out, int n) {
    __shared__ float Asm[32][68];    // [k][row], 64 rows + pad (float4-aligned)
    __shared__ float Wsm[32][132];   // [k][col], pad for 16B alignment
    const int tid = threadIdx.x;
    const int rw = tid >> 4;         // 0..15 -> rows rw*4..rw*4+3
    const int cw = tid & 15;         // cols cw*8
    const int row0 = blockIdx.x * 64;

    float acc[4][8];
    #pragma unroll
    for (int i = 0; i < 4; ++i)
        #pragma unroll
        for (int j = 0; j < 8; ++j) acc[i][j] = 0.f;

    for (int pass = 0; pass < 2; ++pass) {
        const float* A = pass ? H : S;
        const float* __restrict__ W = pass ? Wl : Wn;
        for (int k0 = 0; k0 < 128; k0 += 32) {
            __syncthreads();
            // stage A: 64 rows x 32 k, transposed into LDS (2 float4/thread)
            #pragma unroll
            for (int q = 0; q < 2; ++q) {
                int idx = tid + 256 * q;       // 0..511
                int r = idx >> 3;              // 0..63
                int k4 = (idx & 7) << 2;       // 0,4,..,28
                int gr = row0 + r;
                if (gr >= n) gr = n - 1;
                float4 av = *(const float4*)(A + (size_t)gr * 128 + k0 + k4);
                Asm[k4 + 0][r] = av.x;
                Asm[k4 + 1][r] = av.y;
                Asm[k4 + 2][r] = av.z;
                Asm[k4 + 3][r] = av.w;
            }
            // stage W: 32 k x 128 cols (4 float4/thread)
            #pragma unroll
            for (int q = 0; q < 4; ++q) {
                int idx = tid + 256 * q;       // 0..1023
                int kr = idx >> 5;             // 0..31
                int c4 = (idx & 31) << 2;      // 0..124
                *(float4*)&Wsm[kr][c4] = *(const float4*)(W + (size_t)(k0 + kr) * 128 + c4);
            }
            __syncthreads();
            #pragma unroll
            for (int k = 0; k < 32; ++k) {
                float4 a = *(const float4*)&Asm[k][rw * 4];
                float4 w0 = *(const float4*)&Wsm[k][cw * 8];
                float4 w1 = *(const float4*)&Wsm[k][cw * 8 + 4];
                float av[4] = {a.x, a.y, a.z, a.w};
                float w[8] = {w0.x, w0.y, w0.z, w0.w, w1.x, w1.y, w1.z, w1.w};
                #pragma unroll
                for (int i = 0; i < 4; ++i)
                    #pragma unroll
                    for (int j = 0; j < 8; ++j)
                        acc[i][j] += av[i] * w[j];
            }
        }
    }

    #pragma unroll
    for (int i = 0; i < 4; ++i) {
        int r = row0 + rw * 4 + i;
        if (r < n) {
            float o[8];
            #pragma unroll
            for (int j = 0; j < 8; ++j) {
                float v = acc[i][j];
                o[j] = v >= 0.f ? v : v * SLOPE;
            }
            *(float4*)(out + (size_t)r * 128 + cw * 8)     = make_float4(o[0], o[1], o[2], o[3]);
            *(float4*)(out + (size_t)r * 128 + cw * 8 + 4) = make_float4(o[4], o[5], o[6], o[7]);
        }
    }
}

// Snapshot h rows of alone nodes before the GEMM clobbers them (h may alias out).
__global__ __launch_bounds__(128) void save_alone_kernel(
    const float* __restrict__ H, const int* __restrict__ alone_list,
    const int* __restrict__ alone_count, float* __restrict__ asave) {
    int cnt = *alone_count;
    if (cnt > ALONE_CAP) cnt = ALONE_CAP;
    int t = threadIdx.x;
    for (int i = blockIdx.x; i < cnt; i += gridDim.x) {
        int v = alone_list[i];
        asave[i * 128 + t] = H[v * 128 + t];
    }
}

// For alone nodes: out[v] = leaky(hrow @ Wa). Hrows indexed by node id when
// by_node != 0 (layer 1, reads ent), else by list position (layer 2 snapshot).
__global__ __launch_bounds__(128) void fixup_kernel(
    const float* __restrict__ Hrows, int by_node,
    const float* __restrict__ Wa,
    const int* __restrict__ alone_list, const int* __restrict__ alone_count,
    float* out) {
    int cnt = *alone_count;
    if (cnt > ALONE_CAP) cnt = ALONE_CAP;
    int t = threadIdx.x;
    for (int i = blockIdx.x; i < cnt; i += gridDim.x) {
        int v = alone_list[i];
        const float* hrow = Hrows + (size_t)(by_node ? v : i) * 128;
        float acc = 0.f;
        for (int k = 0; k < 128; ++k)
            acc += hrow[k] * Wa[k * 128 + t];
        out[v * 128 + t] = acc >= 0.f ? acc : acc * SLOPE;
    }
}

extern "C" void kernel_launch(void* const* d_in, const int* in_sizes, int n_in,
                              void* d_out, int out_size, void* d_ws, size_t ws_size,
                              hipStream_t stream) {
    const float* ent  = (const float*)d_in[0];
    const float* rel  = (const float*)d_in[1];
    const float* norm = (const float*)d_in[2];
    const float* Wn   = (const float*)d_in[3];
    const float* Wl   = (const float*)d_in[4];
    const float* Wa   = (const float*)d_in[5];
    const int*   src  = (const int*)d_in[6];
    const int*   dst  = (const int*)d_in[7];
    const int*   ety  = (const int*)d_in[8];
    float* out = (float*)d_out;

    const int n = in_sizes[2];   // 50000
    const int e = in_sizes[7];   // 500000

    // workspace layout
    char* ws = (char*)d_ws;
    int* deg         = (int*)ws;          // n
    int* cursor      = deg + n;           // n
    int* alone_count = cursor + n;        // 1
    size_t zbytes = (size_t)(2 * n + 1) * sizeof(int);
    size_t p = (zbytes + 255) & ~(size_t)255;
    int* row_off = (int*)(ws + p);        // n+1
    p += (((size_t)(n + 1) * 4) + 255) & ~(size_t)255;
    int* partial = (int*)(ws + p);        // <=64
    p += 256;
    int* alone_list = (int*)(ws + p);     // ALONE_CAP
    p += (((size_t)ALONE_CAP * 4) + 255) & ~(size_t)255;
    float* asave = (float*)(ws + p);      // ALONE_CAP*128 floats
    p += (((size_t)ALONE_CAP * 128 * 4) + 255) & ~(size_t)255;
    int2* edges = (int2*)(ws + p);        // e
    p += (((size_t)e * 8) + 255) & ~(size_t)255;
    float* Sbuf = (float*)(ws + p);       // n*128
    float* h1 = out;                      // intermediate h lives in d_out

    const int eb = (e + 255) / 256;
    const int nb = (n + 255) / 256;
    const int nparts = (n + 1023) / 1024;       // 49 (<=64 required)
    const int gb = (n + 63) / 64;               // 782
    const int ab = (n + 3) / 4;                 // 12500

    hipMemsetAsync(ws, 0, zbytes, stream);
    count_kernel<<<eb, 256, 0, stream>>>(dst, deg, e);
    scan_partial_kernel<<<nparts, 256, 0, stream>>>(deg, partial, n);
    scan_aux_kernel<<<1, 64, 0, stream>>>(partial, nparts);
    scan_final_kernel<<<nparts, 256, 0, stream>>>(deg, partial, row_off, n);
    scatter_kernel<<<eb, 256, 0, stream>>>(src, dst, ety, row_off, cursor, edges, e);
    flag_kernel<<<nb, 256, 0, stream>>>(deg, alone_list, alone_count, n);

    // layer 0: h0 = ent -> h1 (in d_out). fixup reads ent (not aliased).
    agg_kernel<<<ab, 256, 0, stream>>>(ent, rel, norm, row_off, edges, Sbuf, n);
    gemm_kernel<<<gb, 256, 0, stream>>>(Sbuf, ent, Wn, Wl, h1, n);
    fixup_kernel<<<16, 128, 0, stream>>>(ent, 1, Wa, alone_list, alone_count, h1);

    // layer 1: h1 -> out (aliases). Snapshot alone rows BEFORE gemm clobbers h1.
    agg_kernel<<<ab, 256, 0, stream>>>(h1, rel, norm, row_off, edges, Sbuf, n);
    save_alone_kernel<<<16, 128, 0, stream>>>(h1, alone_list, alone_count, asave);
    gemm_kernel<<<gb, 256, 0, stream>>>(Sbuf, h1, Wn + 16384, Wl + 16384, out, n);
    fixup_kernel<<<16, 128, 0, stream>>>(asave, 0, Wa + 16384, alone_list, alone_count, out);
}

// Round 5
// 331.009 us; speedup vs baseline: 32.8280x; 1.0797x over previous
//
#include <hip/hip_runtime.h>

#define SLOPE 0.22916666666666666f  // (1/8 + 1/3) / 2
#define ALONE_CAP 2048              // expected alone nodes ~2.3

typedef __attribute__((ext_vector_type(8))) short bfrag;   // 8 x bf16 bits
typedef __attribute__((ext_vector_type(4))) float ffrag;   // 4 x f32 acc

__device__ __forceinline__ unsigned short rne16(float f) {
    unsigned u = __float_as_uint(f);
    return (unsigned short)((u + 0x7FFFu + ((u >> 16) & 1u)) >> 16);
}
__device__ __forceinline__ float bf2f(unsigned short h) {
    return __uint_as_float(((unsigned)h) << 16);
}

// ---------------------------------------------------------------- CSR build
__global__ __launch_bounds__(256) void count_kernel(const int* __restrict__ dst,
                                                    int* __restrict__ deg, int e) {
    int i = blockIdx.x * 256 + threadIdx.x;
    if (i < e) atomicAdd(&deg[dst[i]], 1);
}

__global__ __launch_bounds__(256) void scan_partial_kernel(const int* __restrict__ deg,
                                                           int* __restrict__ partial, int n) {
    __shared__ int wsum[4];
    int base = blockIdx.x * 1024;
    int t = threadIdx.x;
    int s = 0;
    #pragma unroll
    for (int j = 0; j < 4; ++j) {
        int i = base + t + 256 * j;
        if (i < n) s += deg[i];
    }
    #pragma unroll
    for (int off = 1; off < 64; off <<= 1) s += __shfl_xor(s, off, 64);
    if ((t & 63) == 0) wsum[t >> 6] = s;
    __syncthreads();
    if (t == 0) partial[blockIdx.x] = wsum[0] + wsum[1] + wsum[2] + wsum[3];
}

__global__ __launch_bounds__(64) void scan_aux_kernel(int* __restrict__ partial, int nparts) {
    int t = threadIdx.x;  // nparts <= 64
    int v = (t < nparts) ? partial[t] : 0;
    int x = v;
    #pragma unroll
    for (int off = 1; off < 64; off <<= 1) {
        int y = __shfl_up(x, off, 64);
        if (t >= off) x += y;
    }
    if (t < nparts) partial[t] = x - v;  // exclusive
}

// exclusive scan finalize + alone-node detection (deg==0)
__global__ __launch_bounds__(256) void scan_final_kernel(const int* __restrict__ deg,
                                                         const int* __restrict__ partial,
                                                         int* __restrict__ row_off,
                                                         int* __restrict__ alone_list,
                                                         int* __restrict__ alone_count, int n) {
    __shared__ int wsum[4];
    int base = blockIdx.x * 1024;
    int t = threadIdx.x, lane = t & 63, wid = t >> 6;
    int i0 = base + t * 4;
    int v0 = (i0 + 0 < n) ? deg[i0 + 0] : 0;
    int v1 = (i0 + 1 < n) ? deg[i0 + 1] : 0;
    int v2 = (i0 + 2 < n) ? deg[i0 + 2] : 0;
    int v3 = (i0 + 3 < n) ? deg[i0 + 3] : 0;
    int s = v0 + v1 + v2 + v3;
    int x = s;
    #pragma unroll
    for (int off = 1; off < 64; off <<= 1) {
        int y = __shfl_up(x, off, 64);
        if (lane >= off) x += y;
    }
    if (lane == 63) wsum[wid] = x;
    __syncthreads();
    int wbase = 0;
    #pragma unroll
    for (int w = 0; w < 4; ++w) { int ws = wsum[w]; if (w < wid) wbase += ws; }
    int p = partial[blockIdx.x] + wbase + x - s;
    if (i0 + 0 <= n) row_off[i0 + 0] = p;
    p += v0;
    if (i0 + 1 <= n) row_off[i0 + 1] = p;
    p += v1;
    if (i0 + 2 <= n) row_off[i0 + 2] = p;
    p += v2;
    if (i0 + 3 <= n) row_off[i0 + 3] = p;
    // alone detection
    if (i0 + 0 < n && v0 == 0) { int q = atomicAdd(alone_count, 1); if (q < ALONE_CAP) alone_list[q] = i0; }
    if (i0 + 1 < n && v1 == 0) { int q = atomicAdd(alone_count, 1); if (q < ALONE_CAP) alone_list[q] = i0 + 1; }
    if (i0 + 2 < n && v2 == 0) { int q = atomicAdd(alone_count, 1); if (q < ALONE_CAP) alone_list[q] = i0 + 2; }
    if (i0 + 3 < n && v3 == 0) { int q = atomicAdd(alone_count, 1); if (q < ALONE_CAP) alone_list[q] = i0 + 3; }
}

__global__ __launch_bounds__(256) void scatter_kernel(
    const int* __restrict__ src, const int* __restrict__ dst,
    const int* __restrict__ ety, const int* __restrict__ row_off,
    int* __restrict__ cursor, int2* __restrict__ edges, int e) {
    int i = blockIdx.x * 256 + threadIdx.x;
    if (i < e) {
        int v = dst[i];
        int pos = row_off[v] + atomicAdd(&cursor[v], 1);
        edges[pos] = make_int2(src[i], ety[i]);
    }
}

// ------------------------------------------------- bf16 split preparation
// ent fp32 -> hi/lo bf16 arrays (element-wise, float4 granularity)
__global__ __launch_bounds__(256) void split_kernel(const float* __restrict__ x,
                                                    ushort* __restrict__ xh,
                                                    ushort* __restrict__ xl, int total4) {
    int i = blockIdx.x * 256 + threadIdx.x;
    if (i >= total4) return;
    float4 v = ((const float4*)x)[i];
    ushort4 hi, lo;
    hi.x = rne16(v.x); lo.x = rne16(v.x - bf2f(hi.x));
    hi.y = rne16(v.y); lo.y = rne16(v.y - bf2f(hi.y));
    hi.z = rne16(v.z); lo.z = rne16(v.z - bf2f(hi.z));
    hi.w = rne16(v.w); lo.w = rne16(v.w - bf2f(hi.w));
    ((ushort4*)xh)[i] = hi;
    ((ushort4*)xl)[i] = lo;
}

// Pack W[k][n] (128x128 fp32) into MFMA B-fragment order, hi/lo bf16:
// packed[((kc*128 + n)*4 + quad)*8 + j] = bf16(W[kc*32 + quad*8 + j][n])
// mats: 0=Wn L0, 1=Wl L0, 2=Wn L1, 3=Wl L1; out: packW + mat*32768 (hi), +16384 (lo)
__global__ __launch_bounds__(256) void pack_w_kernel(const float* __restrict__ Wn,
                                                     const float* __restrict__ Wl,
                                                     ushort* __restrict__ packW) {
    int t = blockIdx.x * 256 + threadIdx.x;
    if (t >= 4 * 4 * 128 * 4) return;
    int quad = t & 3;
    int nn   = (t >> 2) & 127;
    int kc   = (t >> 9) & 3;
    int mat  = t >> 11;
    const float* W = ((mat & 1) ? Wl : Wn) + (mat >> 1) * 16384;
    ushort* oh = packW + mat * 32768;
    ushort* ol = oh + 16384;
    int obase = ((kc * 128 + nn) * 4 + quad) * 8;
    #pragma unroll
    for (int j = 0; j < 8; ++j) {
        float w = W[(kc * 32 + quad * 8 + j) * 128 + nn];
        unsigned short hi = rne16(w);
        oh[obase + j] = hi;
        ol[obase + j] = rne16(w - bf2f(hi));
    }
}

// ------------------------------------------------------- per-layer kernels
// S[v] = norm[v] * sum_e (h[src]+rel[et]); emitted as bf16 hi/lo split.
__global__ __launch_bounds__(256) void agg_kernel(
    const float* __restrict__ h, const float* __restrict__ rel,
    const float* __restrict__ norm, const int* __restrict__ row_off,
    const int2* __restrict__ edges, ushort* __restrict__ Sh,
    ushort* __restrict__ Sl, int n) {
    int wave = threadIdx.x >> 6, lane = threadIdx.x & 63;
    int v = blockIdx.x * 4 + wave;
    if (v >= n) return;
    int s0 = row_off[v], s1 = row_off[v + 1];
    int half = lane >> 5;
    int c4 = (lane & 31) * 4;
    float4 acc = make_float4(0.f, 0.f, 0.f, 0.f);
    int e = s0;
    for (; e + 1 < s1; e += 2) {
        int2 ed = edges[e + half];
        float4 hv = *(const float4*)&h[(size_t)ed.x * 128 + c4];
        float4 rv = *(const float4*)&rel[(size_t)ed.y * 128 + c4];
        acc.x += hv.x + rv.x; acc.y += hv.y + rv.y;
        acc.z += hv.z + rv.z; acc.w += hv.w + rv.w;
    }
    if (e < s1 && half == 0) {
        int2 ed = edges[e];
        float4 hv = *(const float4*)&h[(size_t)ed.x * 128 + c4];
        float4 rv = *(const float4*)&rel[(size_t)ed.y * 128 + c4];
        acc.x += hv.x + rv.x; acc.y += hv.y + rv.y;
        acc.z += hv.z + rv.z; acc.w += hv.w + rv.w;
    }
    acc.x += __shfl_xor(acc.x, 32, 64);
    acc.y += __shfl_xor(acc.y, 32, 64);
    acc.z += __shfl_xor(acc.z, 32, 64);
    acc.w += __shfl_xor(acc.w, 32, 64);
    if (half == 0) {
        float nm = norm[v];
        acc.x *= nm; acc.y *= nm; acc.z *= nm; acc.w *= nm;
        ushort4 hi, lo;
        hi.x = rne16(acc.x); lo.x = rne16(acc.x - bf2f(hi.x));
        hi.y = rne16(acc.y); lo.y = rne16(acc.y - bf2f(hi.y));
        hi.z = rne16(acc.z); lo.z = rne16(acc.z - bf2f(hi.z));
        hi.w = rne16(acc.w); lo.w = rne16(acc.w - bf2f(hi.w));
        *(ushort4*)&Sh[(size_t)v * 128 + c4] = hi;
        *(ushort4*)&Sl[(size_t)v * 128 + c4] = lo;
    }
}

// out = leaky(S@Wn + H@Wl) via bf16-split MFMA (3 products, fp32 acc). No LDS.
// Block = 256 thr = 4 waves; wave tile 32x64; block tile 64x128. Grid ceil(n/64).
// A operands: Sh/Sl and Hh/Hl bf16 [n][128]. B: pre-packed fragment order.
// Optional epilogue split output Oh/Ol (for h1). Hh/Hl MAY ALIAS Oh/Ol:
// each block touches only its own 64 rows; __syncthreads separates all A
// reads from the epilogue writes (clamped tail rows exist only in last block).
__global__ __launch_bounds__(256) void gemm_mfma_kernel(
    const ushort* __restrict__ Sh, const ushort* __restrict__ Sl,
    const ushort* Hh, const ushort* Hl,
    const ushort* __restrict__ Pnh, const ushort* __restrict__ Pnl,
    const ushort* __restrict__ Plh, const ushort* __restrict__ Pll,
    float* __restrict__ out, ushort* Oh, ushort* Ol, int n) {
    const int tid = threadIdx.x;
    const int wave = tid >> 6, lane = tid & 63;
    const int quad = lane >> 4, l16 = lane & 15;
    const int wr = wave >> 1, wc = wave & 1;
    const int row_base = blockIdx.x * 64 + wr * 32;
    const int col_base = wc * 64;

    // fixed A rows for this lane (clamped; only last block clamps)
    int r0c = row_base + l16;       if (r0c > n - 1) r0c = n - 1;
    int r1c = row_base + 16 + l16;  if (r1c > n - 1) r1c = n - 1;

    int colc[4];
    #pragma unroll
    for (int ct = 0; ct < 4; ++ct) colc[ct] = col_base + ct * 16 + l16;

    ffrag acc[2][4];
    #pragma unroll
    for (int rt = 0; rt < 2; ++rt)
        #pragma unroll
        for (int ct = 0; ct < 4; ++ct) acc[rt][ct] = (ffrag)0.f;

    #pragma unroll 1
    for (int half = 0; half < 2; ++half) {
        const ushort* Ah = half ? Hh : Sh;
        const ushort* Al = half ? Hl : Sl;
        const ushort* Pbh = half ? Plh : Pnh;
        const ushort* Pbl = half ? Pll : Pnl;
        #pragma unroll 1
        for (int kc = 0; kc < 4; ++kc) {
            const int koff = kc * 32 + quad * 8;
            bfrag ah[2], al[2], bh[4], bl[4];
            ah[0] = *(const bfrag*)(Ah + (size_t)r0c * 128 + koff);
            ah[1] = *(const bfrag*)(Ah + (size_t)r1c * 128 + koff);
            al[0] = *(const bfrag*)(Al + (size_t)r0c * 128 + koff);
            al[1] = *(const bfrag*)(Al + (size_t)r1c * 128 + koff);
            #pragma unroll
            for (int ct = 0; ct < 4; ++ct) {
                int bidx = ((kc * 128 + colc[ct]) * 4 + quad) * 8;
                bh[ct] = *(const bfrag*)(Pbh + bidx);
                bl[ct] = *(const bfrag*)(Pbl + bidx);
            }
            #pragma unroll
            for (int rt = 0; rt < 2; ++rt)
                #pragma unroll
                for (int ct = 0; ct < 4; ++ct)
                    acc[rt][ct] = __builtin_amdgcn_mfma_f32_16x16x32_bf16(
                        ah[rt], bh[ct], acc[rt][ct], 0, 0, 0);
            #pragma unroll
            for (int rt = 0; rt < 2; ++rt)
                #pragma unroll
                for (int ct = 0; ct < 4; ++ct)
                    acc[rt][ct] = __builtin_amdgcn_mfma_f32_16x16x32_bf16(
                        ah[rt], bl[ct], acc[rt][ct], 0, 0, 0);
            #pragma unroll
            for (int rt = 0; rt < 2; ++rt)
                #pragma unroll
                for (int ct = 0; ct < 4; ++ct)
                    acc[rt][ct] = __builtin_amdgcn_mfma_f32_16x16x32_bf16(
                        al[rt], bh[ct], acc[rt][ct], 0, 0, 0);
        }
    }

    __syncthreads();  // all A reads done before any epilogue write (alias safety)

    #pragma unroll
    for (int rt = 0; rt < 2; ++rt) {
        #pragma unroll
        for (int ct = 0; ct < 4; ++ct) {
            #pragma unroll
            for (int rg = 0; rg < 4; ++rg) {
                int r = row_base + rt * 16 + quad * 4 + rg;
                if (r < n) {
                    int c = colc[ct];
                    float v = acc[rt][ct][rg];
                    v = v >= 0.f ? v : v * SLOPE;
                    out[(size_t)r * 128 + c] = v;
                    if (Oh) {
                        unsigned short hi = rne16(v);
                        Oh[(size_t)r * 128 + c] = hi;
                        Ol[(size_t)r * 128 + c] = rne16(v - bf2f(hi));
                    }
                }
            }
        }
    }
}

// Snapshot h rows of alone nodes before GEMM-2 clobbers d_out.
__global__ __launch_bounds__(128) void save_alone_kernel(
    const float* __restrict__ H, const int* __restrict__ alone_list,
    const int* __restrict__ alone_count, float* __restrict__ asave) {
    int cnt = *alone_count;
    if (cnt > ALONE_CAP) cnt = ALONE_CAP;
    int t = threadIdx.x;
    for (int i = blockIdx.x; i < cnt; i += gridDim.x) {
        int v = alone_list[i];
        asave[i * 128 + t] = H[v * 128 + t];
    }
}

// Alone nodes: out[v] = leaky(hrow @ Wa); optional bf16-split mirror write.
__global__ __launch_bounds__(128) void fixup_kernel(
    const float* __restrict__ Hrows, int by_node,
    const float* __restrict__ Wa,
    const int* __restrict__ alone_list, const int* __restrict__ alone_count,
    float* out, ushort* Oh, ushort* Ol) {
    int cnt = *alone_count;
    if (cnt > ALONE_CAP) cnt = ALONE_CAP;
    int t = threadIdx.x;
    for (int i = blockIdx.x; i < cnt; i += gridDim.x) {
        int v = alone_list[i];
        const float* hrow = Hrows + (size_t)(by_node ? v : i) * 128;
        float acc = 0.f;
        for (int k = 0; k < 128; ++k)
            acc += hrow[k] * Wa[k * 128 + t];
        float o = acc >= 0.f ? acc : acc * SLOPE;
        out[(size_t)v * 128 + t] = o;
        if (Oh) {
            unsigned short hi = rne16(o);
            Oh[(size_t)v * 128 + t] = hi;
            Ol[(size_t)v * 128 + t] = rne16(o - bf2f(hi));
        }
    }
}

extern "C" void kernel_launch(void* const* d_in, const int* in_sizes, int n_in,
                              void* d_out, int out_size, void* d_ws, size_t ws_size,
                              hipStream_t stream) {
    const float* ent  = (const float*)d_in[0];
    const float* rel  = (const float*)d_in[1];
    const float* norm = (const float*)d_in[2];
    const float* Wn   = (const float*)d_in[3];
    const float* Wl   = (const float*)d_in[4];
    const float* Wa   = (const float*)d_in[5];
    const int*   src  = (const int*)d_in[6];
    const int*   dst  = (const int*)d_in[7];
    const int*   ety  = (const int*)d_in[8];
    float* out = (float*)d_out;

    const int n = in_sizes[2];   // 50000
    const int e = in_sizes[7];   // 500000

    // workspace layout (~57 MB)
    char* ws = (char*)d_ws;
    int* deg         = (int*)ws;          // n
    int* cursor      = deg + n;           // n
    int* alone_count = cursor + n;        // 1
    size_t zbytes = (size_t)(2 * n + 1) * sizeof(int);
    size_t p = (zbytes + 255) & ~(size_t)255;
    int* row_off = (int*)(ws + p);        // n+1
    p += (((size_t)(n + 1) * 4) + 255) & ~(size_t)255;
    int* partial = (int*)(ws + p);        // <=64
    p += 256;
    int* alone_list = (int*)(ws + p);     // ALONE_CAP
    p += (((size_t)ALONE_CAP * 4) + 255) & ~(size_t)255;
    float* asave = (float*)(ws + p);      // ALONE_CAP*128 f32 (1 MB)
    p += (((size_t)ALONE_CAP * 128 * 4) + 255) & ~(size_t)255;
    int2* edges = (int2*)(ws + p);        // e (4 MB)
    p += (((size_t)e * 8) + 255) & ~(size_t)255;
    ushort* Sh = (ushort*)(ws + p);       // n*128 bf16 (12.8 MB)
    p += (((size_t)n * 128 * 2) + 255) & ~(size_t)255;
    ushort* Sl = (ushort*)(ws + p);
    p += (((size_t)n * 128 * 2) + 255) & ~(size_t)255;
    ushort* Eh = (ushort*)(ws + p);       // ent split; reused as h1 split
    p += (((size_t)n * 128 * 2) + 255) & ~(size_t)255;
    ushort* El = (ushort*)(ws + p);
    p += (((size_t)n * 128 * 2) + 255) & ~(size_t)255;
    ushort* packW = (ushort*)(ws + p);    // 4 mats x (hi16K + lo16K) ushorts (256 KB)
    p += 4 * 32768 * 2;
    float* h1 = out;                      // h1 fp32 lives in d_out

    const int eb = (e + 255) / 256;
    const int nparts = (n + 1023) / 1024;       // 49
    const int gb = (n + 63) / 64;               // 782
    const int ab = (n + 3) / 4;                 // 12500
    const int cb = (n * 32 + 255) / 256;        // split_kernel grid (float4 units)

    hipMemsetAsync(ws, 0, zbytes, stream);
    count_kernel<<<eb, 256, 0, stream>>>(dst, deg, e);
    scan_partial_kernel<<<nparts, 256, 0, stream>>>(deg, partial, n);
    scan_aux_kernel<<<1, 64, 0, stream>>>(partial, nparts);
    scan_final_kernel<<<nparts, 256, 0, stream>>>(deg, partial, row_off,
                                                  alone_list, alone_count, n);
    scatter_kernel<<<eb, 256, 0, stream>>>(src, dst, ety, row_off, cursor, edges, e);
    split_kernel<<<cb, 256, 0, stream>>>(ent, Eh, El, n * 32);
    pack_w_kernel<<<32, 256, 0, stream>>>(Wn, Wl, packW);

    // layer 0: ent -> h1 (fp32 in d_out) + h1 split (into Eh/El, aliased w/ sync)
    agg_kernel<<<ab, 256, 0, stream>>>(ent, rel, norm, row_off, edges, Sh, Sl, n);
    gemm_mfma_kernel<<<gb, 256, 0, stream>>>(Sh, Sl, Eh, El,
                                             packW, packW + 16384,
                                             packW + 32768, packW + 49152,
                                             h1, Eh, El, n);
    fixup_kernel<<<16, 128, 0, stream>>>(ent, 1, Wa, alone_list, alone_count,
                                         h1, Eh, El);

    // layer 1: h1 -> out. GEMM-2 reads splits only (never d_out); fixup-2 needs
    // pre-GEMM h1 rows -> snapshot.
    agg_kernel<<<ab, 256, 0, stream>>>(h1, rel, norm, row_off, edges, Sh, Sl, n);
    save_alone_kernel<<<16, 128, 0, stream>>>(h1, alone_list, alone_count, asave);
    gemm_mfma_kernel<<<gb, 256, 0, stream>>>(Sh, Sl, Eh, El,
                                             packW + 65536, packW + 81920,
                                             packW + 98304, packW + 114688,
                                             out, nullptr, nullptr, n);
    fixup_kernel<<<16, 128, 0, stream>>>(asave, 0, Wa + 16384, alone_list, alone_count,
                                         out, nullptr, nullptr);
}

// Round 6
// 307.134 us; speedup vs baseline: 35.3799x; 1.0777x over previous
//
#include <hip/hip_runtime.h>

#define SLOPE 0.22916666666666666f  // (1/8 + 1/3) / 2
#define ALONE_CAP 2048              // expected alone nodes ~2.3

typedef __attribute__((ext_vector_type(8))) short bfrag;   // 8 x bf16 bits
typedef __attribute__((ext_vector_type(4))) float ffrag;   // 4 x f32 acc

__device__ __forceinline__ unsigned short rne16(float f) {
    unsigned u = __float_as_uint(f);
    return (unsigned short)((u + 0x7FFFu + ((u >> 16) & 1u)) >> 16);
}
__device__ __forceinline__ float bf2f(unsigned short h) {
    return __uint_as_float(((unsigned)h) << 16);
}

// ---------------------------------------------------------------- prep
// Fused: [0,eb) count in-degrees; [eb,eb+cb) split ent fp32->bf16 hi/lo;
// [eb+cb, eb+cb+32) pack W into MFMA B-fragment order.
__global__ __launch_bounds__(256) void prep_kernel(
    const int* __restrict__ dst, int* __restrict__ deg, int e, int eb,
    const float* __restrict__ ent, ushort* __restrict__ Eh, ushort* __restrict__ El,
    int total4, int cb,
    const float* __restrict__ Wn, const float* __restrict__ Wl,
    ushort* __restrict__ packW) {
    int b = blockIdx.x;
    if (b < eb) {
        int i = b * 256 + threadIdx.x;
        if (i < e) atomicAdd(&deg[dst[i]], 1);
    } else if (b < eb + cb) {
        int i = (b - eb) * 256 + threadIdx.x;
        if (i >= total4) return;
        float4 v = ((const float4*)ent)[i];
        ushort4 hi, lo;
        hi.x = rne16(v.x); lo.x = rne16(v.x - bf2f(hi.x));
        hi.y = rne16(v.y); lo.y = rne16(v.y - bf2f(hi.y));
        hi.z = rne16(v.z); lo.z = rne16(v.z - bf2f(hi.z));
        hi.w = rne16(v.w); lo.w = rne16(v.w - bf2f(hi.w));
        ((ushort4*)Eh)[i] = hi;
        ((ushort4*)El)[i] = lo;
    } else {
        // packed[((kc*128 + n)*4 + quad)*8 + j] = bf16(W[kc*32 + quad*8 + j][n])
        int t = (b - eb - cb) * 256 + threadIdx.x;
        if (t >= 4 * 4 * 128 * 4) return;
        int quad = t & 3;
        int nn   = (t >> 2) & 127;
        int kc   = (t >> 9) & 3;
        int mat  = t >> 11;   // 0=Wn L0, 1=Wl L0, 2=Wn L1, 3=Wl L1
        const float* W = ((mat & 1) ? Wl : Wn) + (mat >> 1) * 16384;
        ushort* oh = packW + mat * 32768;
        ushort* ol = oh + 16384;
        int obase = ((kc * 128 + nn) * 4 + quad) * 8;
        #pragma unroll
        for (int j = 0; j < 8; ++j) {
            float w = W[(kc * 32 + quad * 8 + j) * 128 + nn];
            unsigned short hi = rne16(w);
            oh[obase + j] = hi;
            ol[obase + j] = rne16(w - bf2f(hi));
        }
    }
}

// --- 3-kernel exclusive scan over deg[n] -> row_off[n+1] (chunk = 1024) ---
__global__ __launch_bounds__(256) void scan_partial_kernel(const int* __restrict__ deg,
                                                           int* __restrict__ partial, int n) {
    __shared__ int wsum[4];
    int base = blockIdx.x * 1024;
    int t = threadIdx.x;
    int s = 0;
    #pragma unroll
    for (int j = 0; j < 4; ++j) {
        int i = base + t + 256 * j;
        if (i < n) s += deg[i];
    }
    #pragma unroll
    for (int off = 1; off < 64; off <<= 1) s += __shfl_xor(s, off, 64);
    if ((t & 63) == 0) wsum[t >> 6] = s;
    __syncthreads();
    if (t == 0) partial[blockIdx.x] = wsum[0] + wsum[1] + wsum[2] + wsum[3];
}

__global__ __launch_bounds__(64) void scan_aux_kernel(int* __restrict__ partial, int nparts) {
    int t = threadIdx.x;  // nparts <= 64
    int v = (t < nparts) ? partial[t] : 0;
    int x = v;
    #pragma unroll
    for (int off = 1; off < 64; off <<= 1) {
        int y = __shfl_up(x, off, 64);
        if (t >= off) x += y;
    }
    if (t < nparts) partial[t] = x - v;  // exclusive
}

// exclusive scan finalize + alone-node detection (deg==0)
__global__ __launch_bounds__(256) void scan_final_kernel(const int* __restrict__ deg,
                                                         const int* __restrict__ partial,
                                                         int* __restrict__ row_off,
                                                         int* __restrict__ alone_list,
                                                         int* __restrict__ alone_count, int n) {
    __shared__ int wsum[4];
    int base = blockIdx.x * 1024;
    int t = threadIdx.x, lane = t & 63, wid = t >> 6;
    int i0 = base + t * 4;
    int v0 = (i0 + 0 < n) ? deg[i0 + 0] : 0;
    int v1 = (i0 + 1 < n) ? deg[i0 + 1] : 0;
    int v2 = (i0 + 2 < n) ? deg[i0 + 2] : 0;
    int v3 = (i0 + 3 < n) ? deg[i0 + 3] : 0;
    int s = v0 + v1 + v2 + v3;
    int x = s;
    #pragma unroll
    for (int off = 1; off < 64; off <<= 1) {
        int y = __shfl_up(x, off, 64);
        if (lane >= off) x += y;
    }
    if (lane == 63) wsum[wid] = x;
    __syncthreads();
    int wbase = 0;
    #pragma unroll
    for (int w = 0; w < 4; ++w) { int ws = wsum[w]; if (w < wid) wbase += ws; }
    int p = partial[blockIdx.x] + wbase + x - s;
    if (i0 + 0 <= n) row_off[i0 + 0] = p;
    p += v0;
    if (i0 + 1 <= n) row_off[i0 + 1] = p;
    p += v1;
    if (i0 + 2 <= n) row_off[i0 + 2] = p;
    p += v2;
    if (i0 + 3 <= n) row_off[i0 + 3] = p;
    if (i0 + 0 < n && v0 == 0) { int q = atomicAdd(alone_count, 1); if (q < ALONE_CAP) alone_list[q] = i0; }
    if (i0 + 1 < n && v1 == 0) { int q = atomicAdd(alone_count, 1); if (q < ALONE_CAP) alone_list[q] = i0 + 1; }
    if (i0 + 2 < n && v2 == 0) { int q = atomicAdd(alone_count, 1); if (q < ALONE_CAP) alone_list[q] = i0 + 2; }
    if (i0 + 3 < n && v3 == 0) { int q = atomicAdd(alone_count, 1); if (q < ALONE_CAP) alone_list[q] = i0 + 3; }
}

// edges packed as uint: src | (ety << 16). Valid because N_ENTS=50000 < 2^16
// and N_RELS=200 < 2^16 for this problem instance.
__global__ __launch_bounds__(256) void scatter_kernel(
    const int* __restrict__ src, const int* __restrict__ dst,
    const int* __restrict__ ety, const int* __restrict__ row_off,
    int* __restrict__ cursor, unsigned* __restrict__ edges, int e) {
    int i = blockIdx.x * 256 + threadIdx.x;
    if (i < e) {
        int v = dst[i];
        int pos = row_off[v] + atomicAdd(&cursor[v], 1);
        edges[pos] = (unsigned)src[i] | ((unsigned)ety[i] << 16);
    }
}

// ------------------------------------------------------- per-layer kernels
// S[v] = norm[v] * sum_e (h[src]+rel[et]); emitted as bf16 hi/lo split.
// One wave per node; half-wave per edge (float4/lane), unroll x2 -> 4 edges
// in flight per wave for memory-level parallelism.
__global__ __launch_bounds__(256) void agg_kernel(
    const float* __restrict__ h, const float* __restrict__ rel,
    const float* __restrict__ norm, const int* __restrict__ row_off,
    const unsigned* __restrict__ edges, ushort* __restrict__ Sh,
    ushort* __restrict__ Sl, int n) {
    int wave = threadIdx.x >> 6, lane = threadIdx.x & 63;
    int v = blockIdx.x * 4 + wave;
    if (v >= n) return;
    int s0 = row_off[v], s1 = row_off[v + 1];
    float nm = norm[v];
    int half = lane >> 5;
    int c4 = (lane & 31) * 4;
    float4 acc = make_float4(0.f, 0.f, 0.f, 0.f);
    int e = s0;
    for (; e + 3 < s1; e += 4) {
        unsigned q0 = edges[e + half];
        unsigned q1 = edges[e + 2 + half];
        const float4* ha0 = (const float4*)&h[(size_t)(q0 & 0xFFFFu) * 128 + c4];
        const float4* ra0 = (const float4*)&rel[(size_t)(q0 >> 16) * 128 + c4];
        const float4* ha1 = (const float4*)&h[(size_t)(q1 & 0xFFFFu) * 128 + c4];
        const float4* ra1 = (const float4*)&rel[(size_t)(q1 >> 16) * 128 + c4];
        float4 h0 = *ha0, r0 = *ra0, h1 = *ha1, r1 = *ra1;
        acc.x += (h0.x + r0.x) + (h1.x + r1.x);
        acc.y += (h0.y + r0.y) + (h1.y + r1.y);
        acc.z += (h0.z + r0.z) + (h1.z + r1.z);
        acc.w += (h0.w + r0.w) + (h1.w + r1.w);
    }
    for (; e + 1 < s1; e += 2) {
        unsigned q0 = edges[e + half];
        float4 h0 = *(const float4*)&h[(size_t)(q0 & 0xFFFFu) * 128 + c4];
        float4 r0 = *(const float4*)&rel[(size_t)(q0 >> 16) * 128 + c4];
        acc.x += h0.x + r0.x; acc.y += h0.y + r0.y;
        acc.z += h0.z + r0.z; acc.w += h0.w + r0.w;
    }
    if (e < s1 && half == 0) {
        unsigned q0 = edges[e];
        float4 h0 = *(const float4*)&h[(size_t)(q0 & 0xFFFFu) * 128 + c4];
        float4 r0 = *(const float4*)&rel[(size_t)(q0 >> 16) * 128 + c4];
        acc.x += h0.x + r0.x; acc.y += h0.y + r0.y;
        acc.z += h0.z + r0.z; acc.w += h0.w + r0.w;
    }
    acc.x += __shfl_xor(acc.x, 32, 64);
    acc.y += __shfl_xor(acc.y, 32, 64);
    acc.z += __shfl_xor(acc.z, 32, 64);
    acc.w += __shfl_xor(acc.w, 32, 64);
    if (half == 0) {
        acc.x *= nm; acc.y *= nm; acc.z *= nm; acc.w *= nm;
        ushort4 hi, lo;
        hi.x = rne16(acc.x); lo.x = rne16(acc.x - bf2f(hi.x));
        hi.y = rne16(acc.y); lo.y = rne16(acc.y - bf2f(hi.y));
        hi.z = rne16(acc.z); lo.z = rne16(acc.z - bf2f(hi.z));
        hi.w = rne16(acc.w); lo.w = rne16(acc.w - bf2f(hi.w));
        *(ushort4*)&Sh[(size_t)v * 128 + c4] = hi;
        *(ushort4*)&Sl[(size_t)v * 128 + c4] = lo;
    }
}

// out = leaky(S@Wn + H@Wl) via bf16-split MFMA (3 products, fp32 acc). No LDS.
// Block = 256 thr = 4 waves; wave tile 32x64; block tile 64x128. Grid ceil(n/64).
// Hh/Hl MAY ALIAS Oh/Ol: each block touches only its own 64 rows; the
// __syncthreads separates all A reads from epilogue writes.
__global__ __launch_bounds__(256) void gemm_mfma_kernel(
    const ushort* __restrict__ Sh, const ushort* __restrict__ Sl,
    const ushort* Hh, const ushort* Hl,
    const ushort* __restrict__ Pnh, const ushort* __restrict__ Pnl,
    const ushort* __restrict__ Plh, const ushort* __restrict__ Pll,
    float* __restrict__ out, ushort* Oh, ushort* Ol, int n) {
    const int tid = threadIdx.x;
    const int wave = tid >> 6, lane = tid & 63;
    const int quad = lane >> 4, l16 = lane & 15;
    const int wr = wave >> 1, wc = wave & 1;
    const int row_base = blockIdx.x * 64 + wr * 32;
    const int col_base = wc * 64;

    int r0c = row_base + l16;       if (r0c > n - 1) r0c = n - 1;
    int r1c = row_base + 16 + l16;  if (r1c > n - 1) r1c = n - 1;

    int colc[4];
    #pragma unroll
    for (int ct = 0; ct < 4; ++ct) colc[ct] = col_base + ct * 16 + l16;

    ffrag acc[2][4];
    #pragma unroll
    for (int rt = 0; rt < 2; ++rt)
        #pragma unroll
        for (int ct = 0; ct < 4; ++ct) acc[rt][ct] = (ffrag)0.f;

    #pragma unroll 1
    for (int half = 0; half < 2; ++half) {
        const ushort* Ah = half ? Hh : Sh;
        const ushort* Al = half ? Hl : Sl;
        const ushort* Pbh = half ? Plh : Pnh;
        const ushort* Pbl = half ? Pll : Pnl;
        #pragma unroll 1
        for (int kc = 0; kc < 4; ++kc) {
            const int koff = kc * 32 + quad * 8;
            bfrag ah[2], al[2], bh[4], bl[4];
            ah[0] = *(const bfrag*)(Ah + (size_t)r0c * 128 + koff);
            ah[1] = *(const bfrag*)(Ah + (size_t)r1c * 128 + koff);
            al[0] = *(const bfrag*)(Al + (size_t)r0c * 128 + koff);
            al[1] = *(const bfrag*)(Al + (size_t)r1c * 128 + koff);
            #pragma unroll
            for (int ct = 0; ct < 4; ++ct) {
                int bidx = ((kc * 128 + colc[ct]) * 4 + quad) * 8;
                bh[ct] = *(const bfrag*)(Pbh + bidx);
                bl[ct] = *(const bfrag*)(Pbl + bidx);
            }
            #pragma unroll
            for (int rt = 0; rt < 2; ++rt)
                #pragma unroll
                for (int ct = 0; ct < 4; ++ct)
                    acc[rt][ct] = __builtin_amdgcn_mfma_f32_16x16x32_bf16(
                        ah[rt], bh[ct], acc[rt][ct], 0, 0, 0);
            #pragma unroll
            for (int rt = 0; rt < 2; ++rt)
                #pragma unroll
                for (int ct = 0; ct < 4; ++ct)
                    acc[rt][ct] = __builtin_amdgcn_mfma_f32_16x16x32_bf16(
                        ah[rt], bl[ct], acc[rt][ct], 0, 0, 0);
            #pragma unroll
            for (int rt = 0; rt < 2; ++rt)
                #pragma unroll
                for (int ct = 0; ct < 4; ++ct)
                    acc[rt][ct] = __builtin_amdgcn_mfma_f32_16x16x32_bf16(
                        al[rt], bh[ct], acc[rt][ct], 0, 0, 0);
        }
    }

    __syncthreads();  // all A reads done before any epilogue write (alias safety)

    #pragma unroll
    for (int rt = 0; rt < 2; ++rt) {
        #pragma unroll
        for (int ct = 0; ct < 4; ++ct) {
            #pragma unroll
            for (int rg = 0; rg < 4; ++rg) {
                int r = row_base + rt * 16 + quad * 4 + rg;
                if (r < n) {
                    int c = colc[ct];
                    float v = acc[rt][ct][rg];
                    v = v >= 0.f ? v : v * SLOPE;
                    out[(size_t)r * 128 + c] = v;
                    if (Oh) {
                        unsigned short hi = rne16(v);
                        Oh[(size_t)r * 128 + c] = hi;
                        Ol[(size_t)r * 128 + c] = rne16(v - bf2f(hi));
                    }
                }
            }
        }
    }
}

// Alone nodes: o = leaky(hrow @ Wa). Layer 0 (by_node=1): reads ent rows by
// node id, writes h1 + split mirrors + asave snapshot (h1[v] for alone v IS
// this o — saves a separate snapshot kernel). Layer 1 (by_node=0): reads
// asave by list position, writes out only.
__global__ __launch_bounds__(128) void fixup_kernel(
    const float* __restrict__ Hrows, int by_node,
    const float* __restrict__ Wa,
    const int* __restrict__ alone_list, const int* __restrict__ alone_count,
    float* out, ushort* Oh, ushort* Ol, float* asave) {
    int cnt = *alone_count;
    if (cnt > ALONE_CAP) cnt = ALONE_CAP;
    int t = threadIdx.x;
    for (int i = blockIdx.x; i < cnt; i += gridDim.x) {
        int v = alone_list[i];
        const float* hrow = Hrows + (size_t)(by_node ? v : i) * 128;
        float acc = 0.f;
        for (int k = 0; k < 128; ++k)
            acc += hrow[k] * Wa[k * 128 + t];
        float o = acc >= 0.f ? acc : acc * SLOPE;
        out[(size_t)v * 128 + t] = o;
        if (Oh) {
            unsigned short hi = rne16(o);
            Oh[(size_t)v * 128 + t] = hi;
            Ol[(size_t)v * 128 + t] = rne16(o - bf2f(hi));
        }
        if (asave) asave[(size_t)i * 128 + t] = o;
    }
}

extern "C" void kernel_launch(void* const* d_in, const int* in_sizes, int n_in,
                              void* d_out, int out_size, void* d_ws, size_t ws_size,
                              hipStream_t stream) {
    const float* ent  = (const float*)d_in[0];
    const float* rel  = (const float*)d_in[1];
    const float* norm = (const float*)d_in[2];
    const float* Wn   = (const float*)d_in[3];
    const float* Wl   = (const float*)d_in[4];
    const float* Wa   = (const float*)d_in[5];
    const int*   src  = (const int*)d_in[6];
    const int*   dst  = (const int*)d_in[7];
    const int*   ety  = (const int*)d_in[8];
    float* out = (float*)d_out;

    const int n = in_sizes[2];   // 50000
    const int e = in_sizes[7];   // 500000

    // workspace layout
    char* ws = (char*)d_ws;
    int* deg         = (int*)ws;          // n
    int* cursor      = deg + n;           // n
    int* alone_count = cursor + n;        // 1
    size_t zbytes = (size_t)(2 * n + 1) * sizeof(int);
    size_t p = (zbytes + 255) & ~(size_t)255;
    int* row_off = (int*)(ws + p);        // n+1
    p += (((size_t)(n + 1) * 4) + 255) & ~(size_t)255;
    int* partial = (int*)(ws + p);        // <=64
    p += 256;
    int* alone_list = (int*)(ws + p);     // ALONE_CAP
    p += (((size_t)ALONE_CAP * 4) + 255) & ~(size_t)255;
    float* asave = (float*)(ws + p);      // ALONE_CAP*128 f32 (1 MB)
    p += (((size_t)ALONE_CAP * 128 * 4) + 255) & ~(size_t)255;
    unsigned* edges = (unsigned*)(ws + p);// e packed (2 MB)
    p += (((size_t)e * 4) + 255) & ~(size_t)255;
    ushort* Sh = (ushort*)(ws + p);       // n*128 bf16 (12.8 MB)
    p += (((size_t)n * 128 * 2) + 255) & ~(size_t)255;
    ushort* Sl = (ushort*)(ws + p);
    p += (((size_t)n * 128 * 2) + 255) & ~(size_t)255;
    ushort* Eh = (ushort*)(ws + p);       // ent split; reused as h1 split
    p += (((size_t)n * 128 * 2) + 255) & ~(size_t)255;
    ushort* El = (ushort*)(ws + p);
    p += (((size_t)n * 128 * 2) + 255) & ~(size_t)255;
    ushort* packW = (ushort*)(ws + p);    // 4 mats x (hi16K + lo16K) (256 KB)
    p += 4 * 32768 * 2;
    float* h1 = out;                      // h1 fp32 lives in d_out

    const int eb = (e + 255) / 256;             // 1954
    const int cb = (n * 32 + 255) / 256;        // 6250 (float4 units)
    const int nparts = (n + 1023) / 1024;       // 49
    const int gb = (n + 63) / 64;               // 782
    const int ab = (n + 3) / 4;                 // 12500

    hipMemsetAsync(ws, 0, zbytes, stream);
    prep_kernel<<<eb + cb + 32, 256, 0, stream>>>(dst, deg, e, eb,
                                                  ent, Eh, El, n * 32, cb,
                                                  Wn, Wl, packW);
    scan_partial_kernel<<<nparts, 256, 0, stream>>>(deg, partial, n);
    scan_aux_kernel<<<1, 64, 0, stream>>>(partial, nparts);
    scan_final_kernel<<<nparts, 256, 0, stream>>>(deg, partial, row_off,
                                                  alone_list, alone_count, n);
    scatter_kernel<<<eb, 256, 0, stream>>>(src, dst, ety, row_off, cursor, edges, e);

    // layer 0: ent -> h1 (fp32 in d_out) + h1 split (into Eh/El, aliased w/ sync)
    agg_kernel<<<ab, 256, 0, stream>>>(ent, rel, norm, row_off, edges, Sh, Sl, n);
    gemm_mfma_kernel<<<gb, 256, 0, stream>>>(Sh, Sl, Eh, El,
                                             packW, packW + 16384,
                                             packW + 32768, packW + 49152,
                                             h1, Eh, El, n);
    fixup_kernel<<<16, 128, 0, stream>>>(ent, 1, Wa, alone_list, alone_count,
                                         h1, Eh, El, asave);

    // layer 1: h1 -> out. GEMM-2 reads splits only; fixup-2 reads asave.
    agg_kernel<<<ab, 256, 0, stream>>>(h1, rel, norm, row_off, edges, Sh, Sl, n);
    gemm_mfma_kernel<<<gb, 256, 0, stream>>>(Sh, Sl, Eh, El,
                                             packW + 65536, packW + 81920,
                                             packW + 98304, packW + 114688,
                                             out, nullptr, nullptr, n);
    fixup_kernel<<<16, 128, 0, stream>>>(asave, 0, Wa + 16384, alone_list, alone_count,
                                         out, nullptr, nullptr, nullptr);
}

// Round 7
// 294.054 us; speedup vs baseline: 36.9536x; 1.0445x over previous
//
#include <hip/hip_runtime.h>

#define SLOPE 0.22916666666666666f  // (1/8 + 1/3) / 2
#define ALONE_CAP 2048              // expected alone nodes ~2.3

typedef __attribute__((ext_vector_type(8))) short bfrag;   // 8 x bf16 bits
typedef __attribute__((ext_vector_type(4))) float ffrag;   // 4 x f32 acc

__device__ __forceinline__ unsigned short rne16(float f) {
    unsigned u = __float_as_uint(f);
    return (unsigned short)((u + 0x7FFFu + ((u >> 16) & 1u)) >> 16);
}
__device__ __forceinline__ float bf2f(unsigned short h) {
    return __uint_as_float(((unsigned)h) << 16);
}
// interleaved split word: hi bf16 in [31:16], lo bf16 in [15:0]
__device__ __forceinline__ unsigned packsplit(float f) {
    unsigned short hi = rne16(f);
    unsigned short lo = rne16(f - bf2f(hi));
    return ((unsigned)hi << 16) | lo;
}
__device__ __forceinline__ float recon(unsigned u) {
    return __uint_as_float(u & 0xFFFF0000u) + __uint_as_float(u << 16);
}
__device__ __forceinline__ float4 recon4(uint4 u) {
    return make_float4(recon(u.x), recon(u.y), recon(u.z), recon(u.w));
}

// ---------------------------------------------------------------- prep
// Fused: [0,eb) count in-degrees; [eb,eb+cb) split ent -> interleaved Esp;
// [eb+cb, +32) pack W into MFMA B-fragment order (hi/lo planes).
__global__ __launch_bounds__(256) void prep_kernel(
    const int* __restrict__ dst, int* __restrict__ deg, int e, int eb,
    const float* __restrict__ ent, unsigned* __restrict__ Esp,
    int total4, int cb,
    const float* __restrict__ Wn, const float* __restrict__ Wl,
    ushort* __restrict__ packW) {
    int b = blockIdx.x;
    if (b < eb) {
        int i = b * 256 + threadIdx.x;
        if (i < e) atomicAdd(&deg[dst[i]], 1);
    } else if (b < eb + cb) {
        int i = (b - eb) * 256 + threadIdx.x;
        if (i >= total4) return;
        float4 v = ((const float4*)ent)[i];
        uint4 w;
        w.x = packsplit(v.x); w.y = packsplit(v.y);
        w.z = packsplit(v.z); w.w = packsplit(v.w);
        ((uint4*)Esp)[i] = w;
    } else {
        // packed[((kc*128 + n)*4 + quad)*8 + j] = bf16(W[kc*32 + quad*8 + j][n])
        int t = (b - eb - cb) * 256 + threadIdx.x;
        if (t >= 4 * 4 * 128 * 4) return;
        int quad = t & 3;
        int nn   = (t >> 2) & 127;
        int kc   = (t >> 9) & 3;
        int mat  = t >> 11;   // 0=Wn L0, 1=Wl L0, 2=Wn L1, 3=Wl L1
        const float* W = ((mat & 1) ? Wl : Wn) + (mat >> 1) * 16384;
        ushort* oh = packW + mat * 32768;
        ushort* ol = oh + 16384;
        int obase = ((kc * 128 + nn) * 4 + quad) * 8;
        #pragma unroll
        for (int j = 0; j < 8; ++j) {
            float w = W[(kc * 32 + quad * 8 + j) * 128 + nn];
            unsigned short hi = rne16(w);
            oh[obase + j] = hi;
            ol[obase + j] = rne16(w - bf2f(hi));
        }
    }
}

// --- scan: partial block sums, then finalize (aux prefix inlined) ---------
__global__ __launch_bounds__(256) void scan_partial_kernel(const int* __restrict__ deg,
                                                           int* __restrict__ partial, int n) {
    __shared__ int wsum[4];
    int base = blockIdx.x * 1024;
    int t = threadIdx.x;
    int s = 0;
    #pragma unroll
    for (int j = 0; j < 4; ++j) {
        int i = base + t + 256 * j;
        if (i < n) s += deg[i];
    }
    #pragma unroll
    for (int off = 1; off < 64; off <<= 1) s += __shfl_xor(s, off, 64);
    if ((t & 63) == 0) wsum[t >> 6] = s;
    __syncthreads();
    if (t == 0) partial[blockIdx.x] = wsum[0] + wsum[1] + wsum[2] + wsum[3];
}

// exclusive scan finalize (computes own block base from partial[]) +
// alone-node detection (deg==0). Requires nparts <= 64.
__global__ __launch_bounds__(256) void scan_final_kernel(const int* __restrict__ deg,
                                                         const int* __restrict__ partial,
                                                         int* __restrict__ row_off,
                                                         int* __restrict__ alone_list,
                                                         int* __restrict__ alone_count, int n) {
    __shared__ int wsum[4];
    __shared__ int sbase;
    int bid = blockIdx.x;
    int t = threadIdx.x, lane = t & 63, wid = t >> 6;
    if (wid == 0) {
        int v = (lane < bid) ? partial[lane] : 0;
        #pragma unroll
        for (int off = 1; off < 64; off <<= 1) v += __shfl_xor(v, off, 64);
        if (lane == 0) sbase = v;
    }
    int base = bid * 1024;
    int i0 = base + t * 4;
    int v0 = (i0 + 0 < n) ? deg[i0 + 0] : 0;
    int v1 = (i0 + 1 < n) ? deg[i0 + 1] : 0;
    int v2 = (i0 + 2 < n) ? deg[i0 + 2] : 0;
    int v3 = (i0 + 3 < n) ? deg[i0 + 3] : 0;
    int s = v0 + v1 + v2 + v3;
    int x = s;
    #pragma unroll
    for (int off = 1; off < 64; off <<= 1) {
        int y = __shfl_up(x, off, 64);
        if (lane >= off) x += y;
    }
    if (lane == 63) wsum[wid] = x;
    __syncthreads();
    int wbase = 0;
    #pragma unroll
    for (int w = 0; w < 4; ++w) { int ws = wsum[w]; if (w < wid) wbase += ws; }
    int p = sbase + wbase + x - s;
    if (i0 + 0 <= n) row_off[i0 + 0] = p;
    p += v0;
    if (i0 + 1 <= n) row_off[i0 + 1] = p;
    p += v1;
    if (i0 + 2 <= n) row_off[i0 + 2] = p;
    p += v2;
    if (i0 + 3 <= n) row_off[i0 + 3] = p;
    if (i0 + 0 < n && v0 == 0) { int q = atomicAdd(alone_count, 1); if (q < ALONE_CAP) alone_list[q] = i0; }
    if (i0 + 1 < n && v1 == 0) { int q = atomicAdd(alone_count, 1); if (q < ALONE_CAP) alone_list[q] = i0 + 1; }
    if (i0 + 2 < n && v2 == 0) { int q = atomicAdd(alone_count, 1); if (q < ALONE_CAP) alone_list[q] = i0 + 2; }
    if (i0 + 3 < n && v3 == 0) { int q = atomicAdd(alone_count, 1); if (q < ALONE_CAP) alone_list[q] = i0 + 3; }
}

// edges packed as uint: src | (ety << 16). Valid: N_ENTS=50000<2^16, N_RELS=200.
__global__ __launch_bounds__(256) void scatter_kernel(
    const int* __restrict__ src, const int* __restrict__ dst,
    const int* __restrict__ ety, const int* __restrict__ row_off,
    int* __restrict__ cursor, unsigned* __restrict__ edges, int e) {
    int i = blockIdx.x * 256 + threadIdx.x;
    if (i < e) {
        int v = dst[i];
        int pos = row_off[v] + atomicAdd(&cursor[v], 1);
        edges[pos] = (unsigned)src[i] | ((unsigned)ety[i] << 16);
    }
}

// ------------------------------------------------------- per-layer kernels
// S[v] = norm[v] * sum_e (h[src]+rel[et]); emitted interleaved hi/lo (Ssp).
// SPLIT=0: h is fp32 (hf). SPLIT=1: h is interleaved split (hs), reconstruct.
// One wave/node; half-wave/edge; 8 edges in flight per wave.
template <int SPLIT>
__global__ __launch_bounds__(256) void agg_kernel(
    const float* __restrict__ hf, const unsigned* __restrict__ hs,
    const float* __restrict__ rel,
    const float* __restrict__ norm, const int* __restrict__ row_off,
    const unsigned* __restrict__ edges, unsigned* __restrict__ Ssp, int n) {
    int wave = threadIdx.x >> 6, lane = threadIdx.x & 63;
    int v = blockIdx.x * 4 + wave;
    if (v >= n) return;
    int s0 = row_off[v], s1 = row_off[v + 1];
    float nm = norm[v];
    int half = lane >> 5;
    int c4 = (lane & 31) * 4;
    float4 acc = make_float4(0.f, 0.f, 0.f, 0.f);
    int e = s0;
    for (; e + 7 < s1; e += 8) {
        unsigned q0 = edges[e + half];
        unsigned q1 = edges[e + 2 + half];
        unsigned q2 = edges[e + 4 + half];
        unsigned q3 = edges[e + 6 + half];
        float4 h0, h1, h2, h3;
        if (SPLIT) {
            h0 = recon4(*(const uint4*)&hs[(size_t)(q0 & 0xFFFFu) * 128 + c4]);
            h1 = recon4(*(const uint4*)&hs[(size_t)(q1 & 0xFFFFu) * 128 + c4]);
            h2 = recon4(*(const uint4*)&hs[(size_t)(q2 & 0xFFFFu) * 128 + c4]);
            h3 = recon4(*(const uint4*)&hs[(size_t)(q3 & 0xFFFFu) * 128 + c4]);
        } else {
            h0 = *(const float4*)&hf[(size_t)(q0 & 0xFFFFu) * 128 + c4];
            h1 = *(const float4*)&hf[(size_t)(q1 & 0xFFFFu) * 128 + c4];
            h2 = *(const float4*)&hf[(size_t)(q2 & 0xFFFFu) * 128 + c4];
            h3 = *(const float4*)&hf[(size_t)(q3 & 0xFFFFu) * 128 + c4];
        }
        float4 r0 = *(const float4*)&rel[(size_t)(q0 >> 16) * 128 + c4];
        float4 r1 = *(const float4*)&rel[(size_t)(q1 >> 16) * 128 + c4];
        float4 r2 = *(const float4*)&rel[(size_t)(q2 >> 16) * 128 + c4];
        float4 r3 = *(const float4*)&rel[(size_t)(q3 >> 16) * 128 + c4];
        acc.x += ((h0.x + r0.x) + (h1.x + r1.x)) + ((h2.x + r2.x) + (h3.x + r3.x));
        acc.y += ((h0.y + r0.y) + (h1.y + r1.y)) + ((h2.y + r2.y) + (h3.y + r3.y));
        acc.z += ((h0.z + r0.z) + (h1.z + r1.z)) + ((h2.z + r2.z) + (h3.z + r3.z));
        acc.w += ((h0.w + r0.w) + (h1.w + r1.w)) + ((h2.w + r2.w) + (h3.w + r3.w));
    }
    for (; e + 1 < s1; e += 2) {
        unsigned q0 = edges[e + half];
        float4 h0 = SPLIT ? recon4(*(const uint4*)&hs[(size_t)(q0 & 0xFFFFu) * 128 + c4])
                          : *(const float4*)&hf[(size_t)(q0 & 0xFFFFu) * 128 + c4];
        float4 r0 = *(const float4*)&rel[(size_t)(q0 >> 16) * 128 + c4];
        acc.x += h0.x + r0.x; acc.y += h0.y + r0.y;
        acc.z += h0.z + r0.z; acc.w += h0.w + r0.w;
    }
    if (e < s1 && half == 0) {
        unsigned q0 = edges[e];
        float4 h0 = SPLIT ? recon4(*(const uint4*)&hs[(size_t)(q0 & 0xFFFFu) * 128 + c4])
                          : *(const float4*)&hf[(size_t)(q0 & 0xFFFFu) * 128 + c4];
        float4 r0 = *(const float4*)&rel[(size_t)(q0 >> 16) * 128 + c4];
        acc.x += h0.x + r0.x; acc.y += h0.y + r0.y;
        acc.z += h0.z + r0.z; acc.w += h0.w + r0.w;
    }
    acc.x += __shfl_xor(acc.x, 32, 64);
    acc.y += __shfl_xor(acc.y, 32, 64);
    acc.z += __shfl_xor(acc.z, 32, 64);
    acc.w += __shfl_xor(acc.w, 32, 64);
    if (half == 0) {
        uint4 w;
        w.x = packsplit(acc.x * nm); w.y = packsplit(acc.y * nm);
        w.z = packsplit(acc.z * nm); w.w = packsplit(acc.w * nm);
        *(uint4*)&Ssp[(size_t)v * 128 + c4] = w;
    }
}

// out = leaky(S@Wn + H@Wl) via bf16-split MFMA (3 products). No LDS.
// Block = 128 thr = 2 waves; wave tile 32 rows x 128 cols (each row fragment
// loaded exactly once). Grid ceil(n/64). A operands are interleaved splits.
// GEMM-1: writes Osp only (h1 split; may alias Hsp — each wave writes only
// rows it read; barrier separates). GEMM-2: writes fp32 out only.
__global__ __launch_bounds__(128) void gemm_mfma_kernel(
    const unsigned* __restrict__ Ssp, const unsigned* Hsp,
    const ushort* __restrict__ Pnh, const ushort* __restrict__ Pnl,
    const ushort* __restrict__ Plh, const ushort* __restrict__ Pll,
    float* __restrict__ out, unsigned* Osp, int n) {
    const int tid = threadIdx.x;
    const int wave = tid >> 6, lane = tid & 63;
    const int quad = lane >> 4, l16 = lane & 15;
    const int row_base = blockIdx.x * 64 + wave * 32;

    int r0c = row_base + l16;       if (r0c > n - 1) r0c = n - 1;
    int r1c = row_base + 16 + l16;  if (r1c > n - 1) r1c = n - 1;

    ffrag acc[2][8];
    #pragma unroll
    for (int rt = 0; rt < 2; ++rt)
        #pragma unroll
        for (int ct = 0; ct < 8; ++ct) acc[rt][ct] = (ffrag)0.f;

    #pragma unroll 1
    for (int half = 0; half < 2; ++half) {
        const unsigned* A = half ? Hsp : Ssp;
        const ushort* Pbh = half ? Plh : Pnh;
        const ushort* Pbl = half ? Pll : Pnl;
        #pragma unroll 1
        for (int kc = 0; kc < 4; ++kc) {
            const int koff = kc * 32 + quad * 8;
            uint4 a0a = *(const uint4*)(A + (size_t)r0c * 128 + koff);
            uint4 a0b = *(const uint4*)(A + (size_t)r0c * 128 + koff + 4);
            uint4 a1a = *(const uint4*)(A + (size_t)r1c * 128 + koff);
            uint4 a1b = *(const uint4*)(A + (size_t)r1c * 128 + koff + 4);
            bfrag ah[2], al[2];
            #pragma unroll
            for (int j = 0; j < 4; ++j) {
                unsigned u0 = ((const unsigned*)&a0a)[j];
                unsigned u1 = ((const unsigned*)&a0b)[j];
                ah[0][j]     = (short)(u0 >> 16); al[0][j]     = (short)(u0 & 0xFFFFu);
                ah[0][j + 4] = (short)(u1 >> 16); al[0][j + 4] = (short)(u1 & 0xFFFFu);
                unsigned u2 = ((const unsigned*)&a1a)[j];
                unsigned u3 = ((const unsigned*)&a1b)[j];
                ah[1][j]     = (short)(u2 >> 16); al[1][j]     = (short)(u2 & 0xFFFFu);
                ah[1][j + 4] = (short)(u3 >> 16); al[1][j + 4] = (short)(u3 & 0xFFFFu);
            }
            bfrag bh[8], bl[8];
            #pragma unroll
            for (int ct = 0; ct < 8; ++ct) {
                int bidx = ((kc * 128 + ct * 16 + l16) * 4 + quad) * 8;
                bh[ct] = *(const bfrag*)(Pbh + bidx);
                bl[ct] = *(const bfrag*)(Pbl + bidx);
            }
            #pragma unroll
            for (int rt = 0; rt < 2; ++rt)
                #pragma unroll
                for (int ct = 0; ct < 8; ++ct)
                    acc[rt][ct] = __builtin_amdgcn_mfma_f32_16x16x32_bf16(
                        ah[rt], bh[ct], acc[rt][ct], 0, 0, 0);
            #pragma unroll
            for (int rt = 0; rt < 2; ++rt)
                #pragma unroll
                for (int ct = 0; ct < 8; ++ct)
                    acc[rt][ct] = __builtin_amdgcn_mfma_f32_16x16x32_bf16(
                        ah[rt], bl[ct], acc[rt][ct], 0, 0, 0);
            #pragma unroll
            for (int rt = 0; rt < 2; ++rt)
                #pragma unroll
                for (int ct = 0; ct < 8; ++ct)
                    acc[rt][ct] = __builtin_amdgcn_mfma_f32_16x16x32_bf16(
                        al[rt], bh[ct], acc[rt][ct], 0, 0, 0);
        }
    }

    __syncthreads();  // all A reads complete before epilogue (Osp may alias Hsp)

    #pragma unroll
    for (int rt = 0; rt < 2; ++rt) {
        #pragma unroll
        for (int ct = 0; ct < 8; ++ct) {
            #pragma unroll
            for (int rg = 0; rg < 4; ++rg) {
                int r = row_base + rt * 16 + quad * 4 + rg;
                if (r < n) {
                    int c = ct * 16 + l16;
                    float v = acc[rt][ct][rg];
                    v = v >= 0.f ? v : v * SLOPE;
                    if (out) out[(size_t)r * 128 + c] = v;
                    if (Osp) Osp[(size_t)r * 128 + c] = packsplit(v);
                }
            }
        }
    }
}

// Alone nodes: o = leaky(hrow @ Wa).
// Layer 0 (by_node=1): hrow = ent[v]; writes Osp (h1 split) + asave fp32.
// Layer 1 (by_node=0): hrow = asave[i]; writes out fp32.
__global__ __launch_bounds__(128) void fixup_kernel(
    const float* __restrict__ Hrows, int by_node,
    const float* __restrict__ Wa,
    const int* __restrict__ alone_list, const int* __restrict__ alone_count,
    float* out, unsigned* Osp, float* asave) {
    int cnt = *alone_count;
    if (cnt > ALONE_CAP) cnt = ALONE_CAP;
    int t = threadIdx.x;
    for (int i = blockIdx.x; i < cnt; i += gridDim.x) {
        int v = alone_list[i];
        const float* hrow = Hrows + (size_t)(by_node ? v : i) * 128;
        float acc = 0.f;
        for (int k = 0; k < 128; ++k)
            acc += hrow[k] * Wa[k * 128 + t];
        float o = acc >= 0.f ? acc : acc * SLOPE;
        if (out) out[(size_t)v * 128 + t] = o;
        if (Osp) Osp[(size_t)v * 128 + t] = packsplit(o);
        if (asave) asave[(size_t)i * 128 + t] = o;
    }
}

extern "C" void kernel_launch(void* const* d_in, const int* in_sizes, int n_in,
                              void* d_out, int out_size, void* d_ws, size_t ws_size,
                              hipStream_t stream) {
    const float* ent  = (const float*)d_in[0];
    const float* rel  = (const float*)d_in[1];
    const float* norm = (const float*)d_in[2];
    const float* Wn   = (const float*)d_in[3];
    const float* Wl   = (const float*)d_in[4];
    const float* Wa   = (const float*)d_in[5];
    const int*   src  = (const int*)d_in[6];
    const int*   dst  = (const int*)d_in[7];
    const int*   ety  = (const int*)d_in[8];
    float* out = (float*)d_out;

    const int n = in_sizes[2];   // 50000
    const int e = in_sizes[7];   // 500000

    // workspace layout
    char* ws = (char*)d_ws;
    int* deg         = (int*)ws;          // n
    int* cursor      = deg + n;           // n
    int* alone_count = cursor + n;        // 1
    size_t zbytes = (size_t)(2 * n + 1) * sizeof(int);
    size_t p = (zbytes + 255) & ~(size_t)255;
    int* row_off = (int*)(ws + p);        // n+1
    p += (((size_t)(n + 1) * 4) + 255) & ~(size_t)255;
    int* partial = (int*)(ws + p);        // <=64
    p += 256;
    int* alone_list = (int*)(ws + p);     // ALONE_CAP
    p += (((size_t)ALONE_CAP * 4) + 255) & ~(size_t)255;
    float* asave = (float*)(ws + p);      // ALONE_CAP*128 f32 (1 MB)
    p += (((size_t)ALONE_CAP * 128 * 4) + 255) & ~(size_t)255;
    unsigned* edges = (unsigned*)(ws + p);// e packed (2 MB)
    p += (((size_t)e * 4) + 255) & ~(size_t)255;
    unsigned* Ssp = (unsigned*)(ws + p);  // n*128 interleaved split (25.6 MB)
    p += (((size_t)n * 128 * 4) + 255) & ~(size_t)255;
    unsigned* Esp = (unsigned*)(ws + p);  // ent split; becomes h1 split (25.6 MB)
    p += (((size_t)n * 128 * 4) + 255) & ~(size_t)255;
    ushort* packW = (ushort*)(ws + p);    // 4 mats x (hi16K + lo16K) (256 KB)
    p += 4 * 32768 * 2;

    const int eb = (e + 255) / 256;             // 1954
    const int cb = (n * 32 + 255) / 256;        // 6250 (float4 units)
    const int nparts = (n + 1023) / 1024;       // 49 (<=64 required)
    const int gb = (n + 63) / 64;               // 782
    const int ab = (n + 3) / 4;                 // 12500

    hipMemsetAsync(ws, 0, zbytes, stream);
    prep_kernel<<<eb + cb + 32, 256, 0, stream>>>(dst, deg, e, eb,
                                                  ent, Esp, n * 32, cb,
                                                  Wn, Wl, packW);
    scan_partial_kernel<<<nparts, 256, 0, stream>>>(deg, partial, n);
    scan_final_kernel<<<nparts, 256, 0, stream>>>(deg, partial, row_off,
                                                  alone_list, alone_count, n);
    scatter_kernel<<<eb, 256, 0, stream>>>(src, dst, ety, row_off, cursor, edges, e);

    // layer 0: ent -> h1 split (in Esp; alias-safe: waves write only rows they read)
    agg_kernel<0><<<ab, 256, 0, stream>>>(ent, nullptr, rel, norm, row_off, edges, Ssp, n);
    gemm_mfma_kernel<<<gb, 128, 0, stream>>>(Ssp, Esp,
                                             packW, packW + 16384,
                                             packW + 32768, packW + 49152,
                                             nullptr, Esp, n);
    fixup_kernel<<<16, 128, 0, stream>>>(ent, 1, Wa, alone_list, alone_count,
                                         nullptr, Esp, asave);

    // layer 1: h1 split -> out (fp32, d_out). fixup-2 reads asave.
    agg_kernel<1><<<ab, 256, 0, stream>>>(nullptr, Esp, rel, norm, row_off, edges, Ssp, n);
    gemm_mfma_kernel<<<gb, 128, 0, stream>>>(Ssp, Esp,
                                             packW + 65536, packW + 81920,
                                             packW + 98304, packW + 114688,
                                             out, nullptr, n);
    fixup_kernel<<<16, 128, 0, stream>>>(asave, 0, Wa + 16384, alone_list, alone_count,
                                         out, nullptr, nullptr);
}